// Round 13
// baseline (30.897 us; speedup 1.0000x reference)
//
#include <hip/hip_runtime.h>

// y[b,o,h,w] = sum_j alphas[o,j] * x[b,j,(128-h)&127,(128-w)&127]
// (FFT2 -> complex channel mix -> IFFT2 collapses to flipped-input channel GEMM;
//  betas contributes only to the imaginary part and drops out.)
//
// Max-TLP lean variant of the r12 kernel (27.8us): wave owns an o-HALF
// (2 acc tiles = 32 VGPR) instead of all 128 o, cutting the wave to a
// 64-VGPR footprint; amdgpu_waves_per_eu(8) pins it -> 8 waves/SIMD,
// 32 waves/CU (2x the previous TLP) to cover load latency with TLP.
// Cost: x columns read twice per block (o-half 0 and 1) -- served by L1/L2
// (r10 measured: HBM FETCH unchanged). Grid 1024 = 4 blocks/CU exactly.
// Everything else r12-proven: depth-2 parity prefetch, single alphas-LDS
// barrier, XOR-swizzled alphas LDS, flip-at-load, nontemporal full-128B-line
// loads and stores.
//
//   D[o][w] = sum_k alphas[o][k] * X[k][w]
//   C/D (m74/m101 + r10..r12-verified): col=lane&31, row=(reg&3)+8*(reg>>2)+4*(lane>>5)
//   A/B k-slots: k = k0 + (lane>>5)*8 + v on BOTH operands (self-consistent).

using bf16   = __bf16;
using bf16x8 = __attribute__((ext_vector_type(8))) __bf16;
using f32x16 = __attribute__((ext_vector_type(16))) float;

// alphas LDS: bf16 [o][k], 256 B rows, 16B-granule XOR swizzle:
//   byte(o,k) = o*256 + (k*2 ^ ((o&7)<<4))   (r7..r12-verified)
static __device__ __forceinline__ int aoff(int o, int k) {
    return o * 256 + ((k * 2) ^ ((o & 7) << 4));
}

__global__ __launch_bounds__(512)
__attribute__((amdgpu_waves_per_eu(8)))
void kk_freqmix_kernel(const float* __restrict__ x,
                       const float* __restrict__ alphas,
                       float* __restrict__ out)
{
    __shared__ unsigned char ldsA[32768];

    const int t   = threadIdx.x;        // 0..511
    const int bid = blockIdx.x;         // 0..1023, one (b,h) tile per block

    const int l   = t & 63;
    const int wv  = t >> 6;             // wave 0..7
    const int oh  = wv >> 2;            // o-half: tiles {oh*2, oh*2+1}
    const int wc  = wv & 3;             // w-chunk [wc*32, +32)
    const int c   = l & 31;             // column within chunk
    const int hi  = l >> 5;             // k-half selector
    const int w   = wc * 32 + c;        // output column this lane produces
    const int ws  = (128 - w) & 127;    // source column (w-flip at load)

    const int b   = bid >> 7;
    const int h   = bid & 127;
    const int hs  = (128 - h) & 127;    // source row (h-flip)

    const float* xcol = x   + (size_t)b * 2097152 + (size_t)hs * 128 + ws;
    float* const op   = out + (size_t)b * 2097152 + (size_t)h  * 128 + w;

    // ---- prologue: issue k-steps 0,1 (16 loads; proven depth 2) ----
    // Per instruction: 32 lanes x 4B contiguous per hi-half = full 128B lines.
    float xv[2][8];
    #pragma unroll
    for (int v = 0; v < 8; ++v) xv[0][v] = xcol[(     hi * 8 + v) * 16384];
    #pragma unroll
    for (int v = 0; v < 8; ++v) xv[1][v] = xcol[(16 + hi * 8 + v) * 16384];

    // ---- stage alphas (64KB fp32 -> 32KB bf16 LDS), once per block ----
    {
        const int o   = t >> 2;         // 0..127
        const int seg = t & 3;          // 32-wide k segment
        const float* ap = alphas + o * 128 + seg * 32;
        #pragma unroll
        for (int j = 0; j < 4; ++j) {
            const float4 a0 = *(const float4*)(ap + j * 8);
            const float4 a1 = *(const float4*)(ap + j * 8 + 4);
            bf16x8 vv;
            vv[0]=(bf16)a0.x; vv[1]=(bf16)a0.y; vv[2]=(bf16)a0.z; vv[3]=(bf16)a0.w;
            vv[4]=(bf16)a1.x; vv[5]=(bf16)a1.y; vv[6]=(bf16)a1.z; vv[7]=(bf16)a1.w;
            *(bf16x8*)(ldsA + aoff(o, seg * 32 + j * 8)) = vv;
        }
    }
    __syncthreads();   // the ONLY barrier; steps 0,1 latency hid under staging

    // ---- k-loop: 8 steps of 16, depth-2 parity prefetch ----
    f32x16 acc[2];     // o-tiles oh*2, oh*2+1
    #pragma unroll
    for (int nt = 0; nt < 2; ++nt)
        #pragma unroll
        for (int r = 0; r < 16; ++r) acc[nt][r] = 0.f;

    #pragma unroll
    for (int st = 0; st < 8; ++st) {
        const int buf = st & 1;
        // consume (B-frag: X[k0 + hi*8 + v][w])
        bf16x8 bfrag;
        #pragma unroll
        for (int v = 0; v < 8; ++v) bfrag[v] = (bf16)xv[buf][v];
        // refill: issue step st+2 into the freed buffer
        if (st + 2 < 8) {
            #pragma unroll
            for (int v = 0; v < 8; ++v)
                xv[buf][v] = xcol[((st + 2) * 16 + hi * 8 + v) * 16384];
        }
        const int k0 = st * 16;
        #pragma unroll
        for (int nt = 0; nt < 2; ++nt) {
            const int o_l = (oh * 2 + nt) * 32 + c;   // A row this lane feeds
            const bf16x8 afrag = *(const bf16x8*)(ldsA + aoff(o_l, k0 + hi * 8));
            acc[nt] = __builtin_amdgcn_mfma_f32_32x32x16_bf16(afrag, bfrag, acc[nt], 0, 0, 0);
        }
    }

    // ---- stores: col(w)=lane&31 -> each instruction writes 2 full 128B lines
    // (hi=0/1 halves hit adjacent o-rows). Nontemporal: keep L3 for reads. ----
    #pragma unroll
    for (int nt = 0; nt < 2; ++nt) {
        const int o_base = (oh * 2 + nt) * 32 + hi * 4;
        #pragma unroll
        for (int r = 0; r < 16; ++r) {
            const int o = o_base + (r & 3) + 8 * (r >> 2);
            __builtin_nontemporal_store(acc[nt][r], op + (size_t)o * 16384);
        }
    }
}

extern "C" void kernel_launch(void* const* d_in, const int* in_sizes, int n_in,
                              void* d_out, int out_size, void* d_ws, size_t ws_size,
                              hipStream_t stream) {
    const float* x      = (const float*)d_in[0];
    const float* alphas = (const float*)d_in[1];
    // betas (d_in[2]) provably unused: contributes only to Im(y), dropped by real().
    float* out = (float*)d_out;

    dim3 grid(1024);   // one (b,h) tile per block; 4 blocks/CU, 32 waves/CU
    dim3 block(512);
    hipLaunchKernelGGL(kk_freqmix_kernel, grid, block, 0, stream, x, alphas, out);
}

// Round 14
// 27.559 us; speedup vs baseline: 1.1212x; 1.1212x over previous
//
#include <hip/hip_runtime.h>

// y[b,o,h,w] = sum_j alphas[o,j] * x[b,j,(128-h)&127,(128-w)&127]
// (FFT2 -> complex channel mix -> IFFT2 collapses to flipped-input channel GEMM;
//  betas contributes only to the imaginary part and drops out.)
//
// Round-12 kernel (27.8us, best) with ONE change: the h-row assigned to each
// block is BIT-REVERSED within the 7-bit row index. All x/out rows live at
// 64KB stride; consecutively-dispatched blocks previously took consecutive h
// (rows 512B apart -> clustered in the low address-interleave bits, i.e. a
// narrow set of L2/HBM channels at any instant). Bit-reversal spreads the
// resident blocks' rows across address bits 9-15 -> all channel groups hit
// concurrently, for both the read and the write stream. Bijective (involution),
// per-block work/layout/traffic unchanged.
//
//   D[o][w] = sum_k alphas[o][k] * X[k][w]
//   C/D (m74/m101 + r10..r12-verified): col=lane&31, row=(reg&3)+8*(reg>>2)+4*(lane>>5)
//   A/B k-slots: k = k0 + (lane>>5)*8 + v on BOTH operands (self-consistent).

using bf16   = __bf16;
using bf16x8 = __attribute__((ext_vector_type(8))) __bf16;
using f32x16 = __attribute__((ext_vector_type(16))) float;

// alphas LDS: bf16 [o][k], 256 B rows, 16B-granule XOR swizzle:
//   byte(o,k) = o*256 + (k*2 ^ ((o&7)<<4))   (r7..r12-verified)
static __device__ __forceinline__ int aoff(int o, int k) {
    return o * 256 + ((k * 2) ^ ((o & 7) << 4));
}

static __device__ __forceinline__ int bitrev7(int v) {
    return ((v & 1) << 6) | ((v & 2) << 4) | ((v & 4) << 2) | (v & 8)
         | ((v & 16) >> 2) | ((v & 32) >> 4) | ((v & 64) >> 6);
}

__global__ __launch_bounds__(512)
__attribute__((amdgpu_waves_per_eu(4, 4)))
void kk_freqmix_kernel(const float* __restrict__ x,
                       const float* __restrict__ alphas,
                       float* __restrict__ out)
{
    __shared__ unsigned char ldsA[32768];

    const int t   = threadIdx.x;        // 0..511
    const int bid = blockIdx.x;         // 0..511, covers 2 h-rows

    const int l   = t & 63;
    const int wv  = t >> 6;             // wave 0..7
    const int hsl = wv >> 2;            // h-row selector within block
    const int wc  = wv & 3;             // w-chunk [wc*32, +32)
    const int c   = l & 31;             // column within chunk
    const int hi  = l >> 5;             // k-half selector
    const int w   = wc * 32 + c;        // output column this lane produces
    const int ws  = (128 - w) & 127;    // source column (w-flip at load)

    const int tile = bid * 2 + hsl;     // 0..1023 (both tiles share batch)
    const int b    = tile >> 7;
    const int h    = bitrev7(tile & 127);  // channel-spreading row permutation
    const int hs   = (128 - h) & 127;      // source row (h-flip)

    const float* xcol = x   + (size_t)b * 2097152 + (size_t)hs * 128 + ws;
    float* const op   = out + (size_t)b * 2097152 + (size_t)h  * 128 + w;

    // ---- prologue: issue k-steps 0,1 (16 loads; r8-proven depth 2) ----
    // Per instruction: 32 lanes x 4B contiguous per hi-half = full 128B lines.
    float xv[2][8];
    #pragma unroll
    for (int v = 0; v < 8; ++v) xv[0][v] = xcol[(     hi * 8 + v) * 16384];
    #pragma unroll
    for (int v = 0; v < 8; ++v) xv[1][v] = xcol[(16 + hi * 8 + v) * 16384];

    // ---- stage alphas (64KB fp32 -> 32KB bf16 LDS), once per block ----
    {
        const int o   = t >> 2;         // 0..127
        const int seg = t & 3;          // 32-wide k segment
        const float* ap = alphas + o * 128 + seg * 32;
        #pragma unroll
        for (int j = 0; j < 4; ++j) {
            const float4 a0 = *(const float4*)(ap + j * 8);
            const float4 a1 = *(const float4*)(ap + j * 8 + 4);
            bf16x8 vv;
            vv[0]=(bf16)a0.x; vv[1]=(bf16)a0.y; vv[2]=(bf16)a0.z; vv[3]=(bf16)a0.w;
            vv[4]=(bf16)a1.x; vv[5]=(bf16)a1.y; vv[6]=(bf16)a1.z; vv[7]=(bf16)a1.w;
            *(bf16x8*)(ldsA + aoff(o, seg * 32 + j * 8)) = vv;
        }
    }
    __syncthreads();   // the ONLY barrier; steps 0,1 latency hid under staging

    // ---- k-loop: 8 steps of 16, depth-2 parity prefetch ----
    f32x16 acc[4];     // o-tiles 0..3 (o = nt*32 + ...)
    #pragma unroll
    for (int nt = 0; nt < 4; ++nt)
        #pragma unroll
        for (int r = 0; r < 16; ++r) acc[nt][r] = 0.f;

    #pragma unroll
    for (int st = 0; st < 8; ++st) {
        const int buf = st & 1;
        // consume (B-frag: X[k0 + hi*8 + v][w])
        bf16x8 bfrag;
        #pragma unroll
        for (int v = 0; v < 8; ++v) bfrag[v] = (bf16)xv[buf][v];
        // refill: issue step st+2 into the freed buffer
        if (st + 2 < 8) {
            #pragma unroll
            for (int v = 0; v < 8; ++v)
                xv[buf][v] = xcol[((st + 2) * 16 + hi * 8 + v) * 16384];
        }
        const int k0 = st * 16;
        #pragma unroll
        for (int nt = 0; nt < 4; ++nt) {
            const int o_l = nt * 32 + c;            // A row this lane feeds
            const bf16x8 afrag = *(const bf16x8*)(ldsA + aoff(o_l, k0 + hi * 8));
            acc[nt] = __builtin_amdgcn_mfma_f32_32x32x16_bf16(afrag, bfrag, acc[nt], 0, 0, 0);
        }
    }

    // ---- stores: col(w)=lane&31 -> each instruction writes 2 full 128B lines
    // (hi=0/1 halves hit adjacent o-rows). Nontemporal: keep L3 for reads. ----
    #pragma unroll
    for (int nt = 0; nt < 4; ++nt) {
        const int o_base = nt * 32 + hi * 4;
        #pragma unroll
        for (int r = 0; r < 16; ++r) {
            const int o = o_base + (r & 3) + 8 * (r >> 2);
            __builtin_nontemporal_store(acc[nt][r], op + (size_t)o * 16384);
        }
    }
}

extern "C" void kernel_launch(void* const* d_in, const int* in_sizes, int n_in,
                              void* d_out, int out_size, void* d_ws, size_t ws_size,
                              hipStream_t stream) {
    const float* x      = (const float*)d_in[0];
    const float* alphas = (const float*)d_in[1];
    // betas (d_in[2]) provably unused: contributes only to Im(y), dropped by real().
    float* out = (float*)d_out;

    dim3 grid(512);    // 2 h-rows per block: 512 * 2 = 1024 tiles
    dim3 block(512);
    hipLaunchKernelGGL(kk_freqmix_kernel, grid, block, 0, stream, x, alphas, out);
}